// Round 12
// baseline (778.249 us; speedup 1.0000x reference)
//
#include <hip/hip_runtime.h>
#include <math.h>

// CV-photonic circuit: WIRES=4, LAYERS=2, CUTOFF=10, BATCH=2048.
// R25 = R24 (wave-uniform conditioning via 50-lane tasks + s_load matrices;
//  598us state / 768 total) + COMMUTE-MERGE ROUND PACKING:
//  R24's conditional passes have 20 tasks over 16 waves -> 2 serial rounds,
//  round 2 only 4/16 waves busy. Gates diagonal on the same control wire
//  commute ({W(0,1),W(0,2),W(0,3)}, {W(1,2),W(1,3)}, {WU(1..3)}); their
//  tasks are round-packed across gates so every round keeps ~16 waves busy
//  (constraint: concurrent tasks never share a control digit; gate-B digit d
//  after gate-A digit d — enforced by round order + barriers):
//   3-gate group: 60 tasks -> 4 rounds (was 6); 2-gate: 40 -> 3 (was 4).
//  Saves ~6 rounds/gen (~8%). Strides are template params per branch
//  (wid branch is wave-uniform -> scalar, compile-time consts).

namespace {

constexpr int NTB = 1024;                 // threads per state block (16 waves)
constexpr int SMEM_STATE = 162352;        // 161584 state + 640 uv + 128 red
constexpr double THETA = 0.7853981633974483096; // pi/4

struct cxf { float x, y; };
typedef float v2f __attribute__((ext_vector_type(2)));
typedef float v4f __attribute__((ext_vector_type(4)));

// ws float layout:
// [0,100)       V    (V[k*10+m]; used directly for the V^T gate)
// [100,200)     VT   (VT[k*10+i] = V[i][k]; used for the V gate)
// [200,1200)    Wt   (10 real 10x10, transposed: Wt[n*100+k*10+i]=W_n[i][k])
// [1200,5000)   BSt  cxf[19*100] zero-padded, transposed
// [5000,6600)   ULt  cxf[8*100]: f=0 (L0 UL0, VT-folded), f=4,5,6 (measure)
// [6600,9800)   stage cxf[16*100] raw S_lay (0..7) / D_lay (8..15)
// [9800,15800)  WUt  cxf[30*100]: WU_{b}[n] transposed, id=(b-1)*10+n
// [15872,...)   u    cxf[B*4*10] encoded per-(b,w) vectors
constexpr int U_OFF = 15872;

__device__ __forceinline__ cxf gen_squeeze_f(int i, int j, float zr, float zi){
  if (j == i+2){ float g = 0.5f*sqrtf((float)((i+1)*(i+2))); return {zr*g, -zi*g}; }
  if (i == j+2){ float g = 0.5f*sqrtf((float)((j+1)*(j+2))); return {-zr*g, -zi*g}; }
  return {0.f, 0.f};
}
__device__ __forceinline__ cxf gen_disp_f(int i, int j, float ar, float ai){
  if (i == j+1){ float g = sqrtf((float)i); return {ar*g, ai*g}; }
  if (j == i+1){ float g = sqrtf((float)j); return {-ar*g, ai*g}; }
  return {0.f, 0.f};
}

// Wave-cooperative fixed-schedule fp32 expm: result = exp(M), n x n (n<=10).
__device__ void expm_f32(bool act, int n, cxf* M, cxf* P, cxf* T, cxf* R, int lane){
  const int n2 = n*n;
  if (act){
    for (int e=lane; e<n2; e+=64){ M[e].x *= 0x1p-10f; M[e].y *= 0x1p-10f; }
    for (int e=lane; e<n2; e+=64){
      P[e] = M[e];
      cxf r = M[e];
      if (e % (n+1) == 0) r.x += 1.f;
      R[e] = r;
    }
  }
  __syncthreads();
  for (int t=2; t<=12; ++t){
    if (act){
      float inv = 1.f/(float)t;
      for (int e=lane; e<n2; e+=64){
        int i = e/n, j = e - i*n;
        float ax=0.f, ay=0.f;
        for (int k=0;k<n;k++){
          cxf p = P[i*n+k], m = M[k*n+j];
          ax += p.x*m.x - p.y*m.y;
          ay += p.x*m.y + p.y*m.x;
        }
        T[e] = {ax*inv, ay*inv};
      }
    }
    __syncthreads();
    { cxf* tmp = P; P = T; T = tmp; }
    if (act){ for (int e=lane; e<n2; e+=64){ R[e].x += P[e].x; R[e].y += P[e].y; } }
    __syncthreads();
  }
  for (int s=0; s<10; ++s){
    if (act){
      for (int e=lane; e<n2; e+=64){
        int i = e/n, j = e - i*n;
        float ax=0.f, ay=0.f;
        for (int k=0;k<n;k++){
          cxf p = R[i*n+k], q = R[k*n+j];
          ax += p.x*q.x - p.y*q.y;
          ay += p.x*q.y + p.y*q.x;
        }
        T[e] = {ax, ay};
      }
    }
    __syncthreads();
    { cxf* tmp = R; R = T; T = tmp; }
    __syncthreads();
  }
}

// ------------- Kernel A: 45 expm tasks fully parallel over 12 blocks -------
__global__ __launch_bounds__(256)
void gates_kernel(const float* __restrict__ dmag, const float* __restrict__ dphase,
                  const float* __restrict__ smag, const float* __restrict__ sphase,
                  float* __restrict__ wsf){
  __shared__ double lam[10];
  __shared__ float scr[4][4][200];      // [wave][buf] cxf[100]
  const int tid = threadIdx.x;
  const int wv = tid >> 6, lane = tid & 63, g = blockIdx.x;
  float* ws_V  = wsf;
  float* ws_VT = wsf + 100;
  float* ws_W  = wsf + 200;
  cxf* ws_BS   = (cxf*)(wsf + 1200);
  cxf* ws_stage= (cxf*)(wsf + 6600);

  if (tid < 10){
    // Division-free Sturm bisection (minor recurrence, sign changes).
    double lo = -6.0, hi = 6.0;
    for (int it=0; it<52; ++it){
      double mid = 0.5*(lo+hi);
      int cnt = 0;
      double pm1 = 1.0;                 // p_0
      double p = -mid;                  // p_1
      if (p == 0.0){ p = -1e-300; }
      if (p < 0.0) cnt++;
      for (int k=2; k<=10; ++k){
        double pn = -mid*p - (double)(k-1)*pm1;
        bool chg = (pn < 0.0) != (p < 0.0);
        if (pn == 0.0){ pn = (p < 0.0) ? 1e-300 : -1e-300; chg = true; }
        if (chg) cnt++;
        pm1 = p; p = pn;
      }
      if (cnt > tid) hi = mid; else lo = mid;
    }
    double x = 0.5*(lo+hi);
    double p[10];
    p[0] = 1.0; p[1] = x;
    for (int k=1;k<9;k++) p[k+1] = (x*p[k] - sqrt((double)k)*p[k-1]) * (1.0/sqrt((double)(k+1)));
    double nn=0.0; for (int k=0;k<10;k++) nn += p[k]*p[k];
    double inv = 1.0/sqrt(nn);
    lam[tid] = x;
    if (g == 0){
      for (int k=0;k<10;k++){
        float v = (float)(p[k]*inv);
        ws_V[k*10+tid]  = v;
        ws_VT[tid*10+k] = v;
      }
    }
  }
  __syncthreads();

  int t = g*4 + wv;
  bool act = (t < 45);
  int n = 10, bn = 0, ilo = 0;
  if (act && t >= 10 && t < 29){
    bn = t - 10; ilo = bn < 10 ? 0 : bn - 9;
    int ihi = bn < 10 ? bn : 9;
    n = ihi - ilo + 1;
  }
  cxf* M = (cxf*)scr[wv][0];
  cxf* P = (cxf*)scr[wv][1];
  cxf* T = (cxf*)scr[wv][2];
  cxf* R = (cxf*)scr[wv][3];
  if (act){
    if (t < 10){
      float l = (float)lam[t];   // Q = -0.5*(a - ad)
      for (int e=lane; e<100; e+=64){
        int i=e/10, j=e-10*i;
        float v = 0.f;
        if (j == i+1) v = -0.5f*l*sqrtf((float)(i+1));
        else if (i == j+1) v = 0.5f*l*sqrtf((float)i);
        M[e] = {v, 0.f};
      }
    } else if (t < 29){
      for (int e=lane; e<n*n; e+=64){
        int rr=e/n, c=e-n*rr;
        float v = 0.f;
        if (c == rr+1) v = (float)THETA*sqrtf((float)((ilo+rr+1)*(bn-ilo-rr)));
        else if (rr == c+1) v = (float)THETA*sqrtf((float)((ilo+c+1)*(bn-ilo-c)));
        M[e] = {0.f, v};
      }
    } else {
      int idx = t-29, kind = idx>>3, L=(idx>>2)&1, w=idx&3;
      float r_ = kind ? dmag[L*4+w]   : smag[L*4+w];
      float ph = kind ? dphase[L*4+w] : sphase[L*4+w];
      float zr = r_*cosf(ph), zi = r_*sinf(ph);
      for (int e=lane; e<100; e+=64){
        int i=e/10, j=e-10*i;
        M[e] = kind ? gen_disp_f(i,j,zr,zi) : gen_squeeze_f(i,j,zr,zi);
      }
    }
  }
  __syncthreads();
  expm_f32(act, n, M, P, T, R, lane);
  if (act){
    if (t < 10){
      for (int e=lane;e<100;e+=64){
        int i=e/10, j=e-10*i;
        ws_W[t*100 + j*10 + i] = R[e].x;   // transposed, real
      }
    } else if (t < 29){
      for (int e=lane;e<100;e+=64){
        int rr=e/10, c=e-10*rr;
        cxf o; o.x=0.f; o.y=0.f;
        if (rr < n && c < n) o = R[rr*n+c];
        ws_BS[bn*100 + c*10 + rr] = o;     // zero-padded + transposed
      }
    } else {
      int idx = t-29;
      for (int e=lane;e<100;e+=64) ws_stage[idx*100 + e] = R[e];
    }
  }
}

// ---- Kernel A2: UL products, VT fold, and WU_b[n] = W_n * UL_b fusion -----
__global__ __launch_bounds__(512)
void fuse_kernel(float* __restrict__ wsf){
  __shared__ cxf ulraw[8][100];          // raw UL[f] = D*S, [i*10+j]
  const int tid = threadIdx.x, wv = tid>>6, lane = tid&63;
  const cxf* stage = (const cxf*)(wsf + 6600);
  cxf* ws_UL = (cxf*)(wsf + 5000);
  cxf* ws_WU = (cxf*)(wsf + 9800);
  const float* V  = wsf;
  const float* Wt = wsf + 200;
  const cxf* Sm = stage + wv*100;
  const cxf* Dm = stage + (8+wv)*100;
  for (int e=lane; e<100; e+=64){
    int i=e/10, j=e-10*i;
    float ax=0.f, ay=0.f;
    for (int k=0;k<10;k++){
      cxf d=Dm[i*10+k], s=Sm[k*10+j];
      ax += d.x*s.x - d.y*s.y;
      ay += d.x*s.y + d.y*s.x;
    }
    ulraw[wv][e] = {ax, ay};
  }
  __syncthreads();
  // f=0 only: UL0 <- V^T * UL0 (carries L1's V0^T). Two elems per lane.
  cxf t0={0.f,0.f}, t1={0.f,0.f};
  if (wv == 0){
    {
      int e=lane, i=e/10, j=e-10*i;
      float ox=0.f, oy=0.f;
      for (int k=0;k<10;k++){ float v=V[k*10+i]; ox+=v*ulraw[0][k*10+j].x; oy+=v*ulraw[0][k*10+j].y; }
      t0 = {ox, oy};
    }
    if (lane+64 < 100){
      int e=lane+64, i=e/10, j=e-10*i;
      float ox=0.f, oy=0.f;
      for (int k=0;k<10;k++){ float v=V[k*10+i]; ox+=v*ulraw[0][k*10+j].x; oy+=v*ulraw[0][k*10+j].y; }
      t1 = {ox, oy};
    }
  }
  __syncthreads();
  if (wv == 0){
    ulraw[0][lane] = t0;
    if (lane+64 < 100) ulraw[0][lane+64] = t1;
  }
  __syncthreads();
  // Export ULt (transposed) for f in {0,4,5,6}
  for (int e=tid; e<400; e+=512){
    int fi = e/100, r = e-100*fi;
    int f = (fi==0) ? 0 : (3+fi);        // 0,4,5,6
    int i=r/10, j=r-10*i;
    ws_UL[f*100 + j*10 + i] = ulraw[f][i*10+j];
  }
  // Phase 2: WU_b[n] = W_n * ulraw[b], id=(b-1)*10+n, 30 tasks over 8 waves.
  for (int round=0; round<4; ++round){
    int id = round*8 + wv;
    if (id < 30){
      int b = 1 + id/10, n = id - (id/10)*10;
      const cxf* Ub = ulraw[b];
      for (int e=lane; e<100; e+=64){
        int i=e/10, j=e-10*i;
        float ax=0.f, ay=0.f;
        for (int k=0;k<10;k++){
          float w = Wt[n*100 + k*10 + i];   // W_n[i][k]
          ax += w*Ub[k*10+j].x;
          ay += w*Ub[k*10+j].y;
        }
        cxf o; o.x=ax; o.y=ay;
        ws_WU[id*100 + j*10 + i] = o;       // transposed
      }
    }
  }
}

// ------------- Kernel B: per-(b,w) encoding vector u = D*(S*e0), fp32 ------
__global__ __launch_bounds__(128)
void enc_kernel(const float* __restrict__ jets, const float* __restrict__ sscale,
                float* __restrict__ wsf){
  __shared__ float scr[2][4][200];
  __shared__ cxf col[10];
  __shared__ cxf uacc[10];
  const int tid = threadIdx.x, wv = tid>>6, lane = tid&63;
  const int blk = blockIdx.x, b = blk>>2, w = blk&3;

  float eta = jets[b*12 + w*3 + 0];
  float jph = jets[b*12 + w*3 + 1];
  float pt  = jets[b*12 + w*3 + 2];

  cxf* M = (cxf*)scr[wv][0];
  cxf* P = (cxf*)scr[wv][1];
  cxf* T = (cxf*)scr[wv][2];
  cxf* R = (cxf*)scr[wv][3];
  {
    float zr, zi;
    if (wv == 0){ float phs = pt*jph*0.5f; zr = eta*cosf(phs); zi = eta*sinf(phs); }
    else {
      double sc = 10.0/(1.0 + exp(-(double)sscale[0])) + 0.01;
      float mag = (float)sc*pt; zr = mag*cosf(eta); zi = mag*sinf(eta);
    }
    for (int e=lane; e<100; e+=64){
      int i=e/10, j=e-10*i;
      M[e] = wv ? gen_disp_f(i,j,zr,zi) : gen_squeeze_f(i,j,zr,zi);
    }
  }
  __syncthreads();
  expm_f32(true, 10, M, P, T, R, lane);
  cxf* Rs = (cxf*)scr[0][3];
  cxf* Rd = (cxf*)scr[1][3];
  if (tid < 10) col[tid] = Rs[tid*10];           // squeeze column 0
  __syncthreads();
  if (tid < 10){
    float ax=0.f, ay=0.f;
    for (int k=0;k<10;k++){
      cxf d = Rd[tid*10+k], c = col[k];
      ax += d.x*c.x - d.y*c.y;
      ay += d.x*c.y + d.y*c.x;
    }
    uacc[tid] = {ax, ay};
  }
  __syncthreads();
  if (tid < 10){
    float rx, ry;
    if (w == 0){
      rx = 0.f; ry = 0.f;
      for (int k=0;k<10;k++){
        float v = wsf[k*10 + tid];               // (V^T)[tid][k]
        rx += v*uacc[k].x;
        ry += v*uacc[k].y;
      }
    } else { rx = uacc[tid].x; ry = uacc[tid].y; }
    float* u_out = wsf + U_OFF + (b*40 + w*10 + tid)*2;
    u_out[0] = rx;
    u_out[1] = ry;
  }
}

// ---------------- Kernel C: the circuit, 2 states/block, v4f LDS -----------
// Padded digit strides: element (c0,c1,c2,c3) -> c0*1010 + c1*101 + c2*10 + c3.
__device__ __forceinline__ constexpr int WS(int w){
  return w==0 ? 1010 : (w==1 ? 101 : (w==2 ? 10 : 1));
}

#define DECLP(P) v4f P##0={0.f,0.f,0.f,0.f}, P##1=P##0, P##2=P##0, P##3=P##0, \
  P##4=P##0, P##5=P##0, P##6=P##0, P##7=P##0, P##8=P##0, P##9=P##0;

#define REX(O,i,u) O##i = __builtin_elementwise_fma((v4f){(u),(u),(u),(u)}, vv, O##i);

#define RPAIRX(O, va, vb, Mp_) { \
  const v4f* Mp = (Mp_); \
  v4f q0=Mp[0],q1=Mp[1],q2=Mp[2],q3=Mp[3],q4=Mp[4]; \
  { v4f vv=va; REX(O,0,q0.x) REX(O,1,q0.y) REX(O,2,q0.z) REX(O,3,q0.w) REX(O,4,q1.x) \
               REX(O,5,q1.y) REX(O,6,q1.z) REX(O,7,q1.w) REX(O,8,q2.x) REX(O,9,q2.y) } \
  { v4f vv=vb; REX(O,0,q2.z) REX(O,1,q2.w) REX(O,2,q3.x) REX(O,3,q3.y) REX(O,4,q3.z) \
               REX(O,5,q3.w) REX(O,6,q4.x) REX(O,7,q4.y) REX(O,8,q4.z) REX(O,9,q4.w) } }

#define RSTAGE(Mt, I, O) \
  RPAIRX(O, I##0, I##1, (const v4f*)((Mt)+0))  \
  RPAIRX(O, I##2, I##3, (const v4f*)((Mt)+20)) \
  RPAIRX(O, I##4, I##5, (const v4f*)((Mt)+40)) \
  RPAIRX(O, I##6, I##7, (const v4f*)((Mt)+60)) \
  RPAIRX(O, I##8, I##9, (const v4f*)((Mt)+80))

#define CEX(O,i,ur,ui) \
  O##i = __builtin_elementwise_fma((v4f){(ur),(ur),(ur),(ur)}, vv, O##i); \
  O##i = __builtin_elementwise_fma((v4f){-(ui),(ui),-(ui),(ui)}, vs, O##i);

#define CROWX(O, vk, Up_) { \
  const v4f* Up = (Up_); \
  v4f q0=Up[0],q1=Up[1],q2=Up[2],q3=Up[3],q4=Up[4]; \
  v4f vv=vk, vs=__builtin_shufflevector(vk,vk,1,0,3,2); \
  CEX(O,0,q0.x,q0.y) CEX(O,1,q0.z,q0.w) CEX(O,2,q1.x,q1.y) CEX(O,3,q1.z,q1.w) \
  CEX(O,4,q2.x,q2.y) CEX(O,5,q2.z,q2.w) CEX(O,6,q3.x,q3.y) CEX(O,7,q3.z,q3.w) \
  CEX(O,8,q4.x,q4.y) CEX(O,9,q4.z,q4.w) }

// measure variant: output row 0 (photon number 0, weight 0) skipped.
#define CROWX9(O, vk, Up_) { \
  const v4f* Up = (Up_); \
  v4f q0=Up[0],q1=Up[1],q2=Up[2],q3=Up[3],q4=Up[4]; \
  v4f vv=vk, vs=__builtin_shufflevector(vk,vk,1,0,3,2); \
  CEX(O,1,q0.z,q0.w) CEX(O,2,q1.x,q1.y) CEX(O,3,q1.z,q1.w) \
  CEX(O,4,q2.x,q2.y) CEX(O,5,q2.z,q2.w) CEX(O,6,q3.x,q3.y) CEX(O,7,q3.z,q3.w) \
  CEX(O,8,q4.x,q4.y) CEX(O,9,q4.z,q4.w) }

#define CSTAGE(U, I, O) \
  CROWX(O, I##0, (const v4f*)((U)+0))  CROWX(O, I##1, (const v4f*)((U)+10)) \
  CROWX(O, I##2, (const v4f*)((U)+20)) CROWX(O, I##3, (const v4f*)((U)+30)) \
  CROWX(O, I##4, (const v4f*)((U)+40)) CROWX(O, I##5, (const v4f*)((U)+50)) \
  CROWX(O, I##6, (const v4f*)((U)+60)) CROWX(O, I##7, (const v4f*)((U)+70)) \
  CROWX(O, I##8, (const v4f*)((U)+80)) CROWX(O, I##9, (const v4f*)((U)+90))

#define CSTAGE9(U, I, O) \
  CROWX9(O, I##0, (const v4f*)((U)+0))  CROWX9(O, I##1, (const v4f*)((U)+10)) \
  CROWX9(O, I##2, (const v4f*)((U)+20)) CROWX9(O, I##3, (const v4f*)((U)+30)) \
  CROWX9(O, I##4, (const v4f*)((U)+40)) CROWX9(O, I##5, (const v4f*)((U)+50)) \
  CROWX9(O, I##6, (const v4f*)((U)+60)) CROWX9(O, I##7, (const v4f*)((U)+70)) \
  CROWX9(O, I##8, (const v4f*)((U)+80)) CROWX9(O, I##9, (const v4f*)((U)+90))

#define LDS_RD10 \
  v4f r0=S[base], r1=S[base+sm], r2=S[base+2*sm], r3=S[base+3*sm], r4=S[base+4*sm], \
      r5=S[base+5*sm], r6=S[base+6*sm], r7=S[base+7*sm], r8=S[base+8*sm], r9=S[base+9*sm];

#define PSTORE10(P) { S[base]=P##0; S[base+sm]=P##1; S[base+2*sm]=P##2; S[base+3*sm]=P##3; \
  S[base+4*sm]=P##4; S[base+5*sm]=P##5; S[base+6*sm]=P##6; S[base+7*sm]=P##7; \
  S[base+8*sm]=P##8; S[base+9*sm]=P##9; }

// ---- wave-uniform conditional tasks (compile-time strides) ----------------
// Task t in [0,20): cond digit n = t>>1 (wave-uniform), half = t&1.
// 50 lanes handle fibers f = half*50 + lane over spectators (qa,qb).
template<int SC,int SM,int SA,int SB>
__device__ __forceinline__ void Wtask_t(v4f* S, const float* __restrict__ Wall,
                                        int t, int lane){
  int n = t>>1, half = t&1;
  if (lane < 50){
    int f = half*50 + lane;
    int qa = f/10, qb = f - 10*qa;
    int base = n*SC + qa*SA + qb*SB;
    const float* __restrict__ Mt = Wall + n*100;   // n uniform -> s_load
    const int sm = SM;
    LDS_RD10
    DECLP(a) RSTAGE(Mt, r, a)
    PSTORE10(a)
  }
}
template<int SC,int SM,int SA,int SB>
__device__ __forceinline__ void WUtask_t(v4f* S, const cxf* __restrict__ WUb,
                                         int t, int lane){
  int n = t>>1, half = t&1;
  if (lane < 50){
    int f = half*50 + lane;
    int qa = f/10, qb = f - 10*qa;
    int base = n*SC + qa*SA + qb*SB;
    const cxf* __restrict__ U = WUb + n*100;       // n uniform -> s_load
    const int sm = SM;
    LDS_RD10
    DECLP(a) CSTAGE(U, r, a)
    PSTORE10(a)
  }
}

// Commute-merged group: {W(0,1),W(0,2),W(0,3)} — all diagonal on c0.
// 60 tasks packed into 4 rounds; concurrent tasks never share a digit,
// gate-B digit d always after gate-A digit d.
__device__ __forceinline__ void groupW0(v4f* S, const float* __restrict__ Wm,
                                        int wid, int lane){
  Wtask_t<1010,101,10,1>(S, Wm, wid, lane);                 // W01 d0-7
  __syncthreads();
  if (wid < 4) Wtask_t<1010,101,10,1>(S, Wm, 16+wid, lane); // W01 d8,9
  else         Wtask_t<1010,10,101,1>(S, Wm, wid-4, lane);  // W02 d0-5
  __syncthreads();
  if (wid < 8) Wtask_t<1010,10,101,1>(S, Wm, 12+wid, lane); // W02 d6-9
  else         Wtask_t<1010,1,10,101>(S, Wm, wid-8, lane);  // W03 d0-3 (swap)
  __syncthreads();
  if (wid < 12) Wtask_t<1010,1,10,101>(S, Wm, 8+wid, lane); // W03 d4-9
}
// {WU(1),WU(2),WU(3)} — complex, same packing.
__device__ __forceinline__ void groupWU0(v4f* S, const cxf* __restrict__ WUm,
                                         int wid, int lane){
  WUtask_t<1010,101,10,1>(S, WUm, wid, lane);
  __syncthreads();
  if (wid < 4) WUtask_t<1010,101,10,1>(S, WUm, 16+wid, lane);
  else         WUtask_t<1010,10,101,1>(S, WUm+1000, wid-4, lane);
  __syncthreads();
  if (wid < 8) WUtask_t<1010,10,101,1>(S, WUm+1000, 12+wid, lane);
  else         WUtask_t<1010,1,10,101>(S, WUm+2000, wid-8, lane);
  __syncthreads();
  if (wid < 12) WUtask_t<1010,1,10,101>(S, WUm+2000, 8+wid, lane);
}
// {W(1,2),W(1,3)} — diagonal on c1; 40 tasks in 3 rounds.
__device__ __forceinline__ void groupW1(v4f* S, const float* __restrict__ Wm,
                                        int wid, int lane){
  Wtask_t<101,10,1010,1>(S, Wm, wid, lane);                 // W12 d0-7
  __syncthreads();
  if (wid < 4) Wtask_t<101,10,1010,1>(S, Wm, 16+wid, lane); // W12 d8,9
  else         Wtask_t<101,1,1010,10>(S, Wm, wid-4, lane);  // W13 d0-5
  __syncthreads();
  if (wid < 8) Wtask_t<101,1,1010,10>(S, Wm, 12+wid, lane); // W13 d6-9
}
// Single conditional pass (W(2,3)): 20 tasks, 2 rounds (no internal barrier —
// all tasks disjoint).
__device__ __forceinline__ void applyW23(v4f* S, const float* __restrict__ Wm,
                                         int wid, int lane){
  Wtask_t<10,1,1010,101>(S, Wm, wid, lane);
  if (wid < 4) Wtask_t<10,1,1010,101>(S, Wm, 16+wid, lane);
}

// BS task t in [0,38): bn = t>>1 (wave-uniform -> uniform sz loop), half = t&1.
__device__ __forceinline__ void do_BStask(v4f* S, const cxf* __restrict__ BSp,
                                          int sa, int sb, int s1, int s2, int ds,
                                          int t, int lane){
  int bn = t>>1, half = t&1;
  int ilo = bn<10?0:bn-9, ihi = bn<10?bn:9, sz = ihi-ilo+1;
  if (lane < 50){
    int f = half*50 + lane;
    int ca = f/10, cb = f - 10*ca;
    int base = ca*sa + cb*sb;
    const cxf* __restrict__ Bt = BSp + bn*100;     // bn uniform -> s_load
    DECLP(a)
    int radr = base + ilo*s1 + (bn-ilo)*s2;
    int kk = 0;
    #pragma unroll 1
    for (int c=0;c<sz;c++){
      v4f rk = S[radr];
      CROWX(a, rk, (const v4f*)(Bt + kk))
      radr += ds; kk += 10;
    }
    int wadr = base + ilo*s1 + (bn-ilo)*s2;
    #define BSTQ(r) if ((r) < sz){ S[wadr] = a##r; wadr += ds; }
    BSTQ(0) BSTQ(1) BSTQ(2) BSTQ(3) BSTQ(4) BSTQ(5) BSTQ(6) BSTQ(7) BSTQ(8) BSTQ(9)
    #undef BSTQ
  }
}
__device__ __forceinline__ void applyBS_u(v4f* S, const cxf* __restrict__ BSp,
                                          int sa, int sb, int s1, int s2,
                                          int wid, int lane){
  const int ds = s1 - s2;
  do_BStask(S, BSp, sa, sb, s1, s2, ds, wid, lane);
  do_BStask(S, BSp, sa, sb, s1, s2, ds, wid+16, lane);
  if (wid < 6) do_BStask(S, BSp, sa, sb, s1, s2, ds, wid+32, lane);
}

// ---- uniform single-wire passes (full 1024-thread map) --------------------
__device__ __forceinline__ void apply1_r4(v4f* S, const float* __restrict__ Mt, int m, int tid){
  const int sm = WS(m);
  const int x0 = (m==0)?1:0, x1=(m<=1)?2:1, x2=(m<=2)?3:2;
  const int s0 = WS(x0), s1 = WS(x1), s2 = WS(x2);
  if (tid < 1000){
    int d0=tid/100, rem=tid-100*d0, d1=rem/10, d2=rem-10*d1;
    int base = d0*s0 + d1*s1 + d2*s2;
    LDS_RD10
    DECLP(a) RSTAGE(Mt, r, a)
    PSTORE10(a)
  }
}

__device__ __forceinline__ void apply1_c4(v4f* S, const cxf* __restrict__ U, int m, int tid){
  const int sm = WS(m);
  const int x0 = (m==0)?1:0, x1=(m<=1)?2:1, x2=(m<=2)?3:2;
  const int s0 = WS(x0), s1 = WS(x1), s2 = WS(x2);
  if (tid < 1000){
    int d0=tid/100, rem=tid-100*d0, d1=rem/10, d2=rem-10*d1;
    int base = d0*s0 + d1*s1 + d2*s2;
    LDS_RD10
    DECLP(a) CSTAGE(U, r, a)
    PSTORE10(a)
  }
}

// Read-only measure: per-state sum_i i*|(U v)_i|^2; output row 0 skipped.
__device__ __forceinline__ v2f measure14(const v4f* S, const cxf* __restrict__ U, int m, int tid){
  const int sm = WS(m);
  const int x0 = (m==0)?1:0, x1=(m<=1)?2:1, x2=3;
  const int s0 = WS(x0), s1 = WS(x1), s2 = WS(x2);
  v2f s = {0.f, 0.f};
  if (tid < 1000){
    int d0=tid/100, rem=tid-100*d0, d1=rem/10, d2=rem-10*d1;
    int base = d0*s0 + d1*s1 + d2*s2;
    LDS_RD10
    DECLP(a) CSTAGE9(U, r, a)
    #define MQ4(i) { s.x += (float)(i)*(a##i.x*a##i.x + a##i.y*a##i.y); \
                     s.y += (float)(i)*(a##i.z*a##i.z + a##i.w*a##i.w); }
    MQ4(1) MQ4(2) MQ4(3) MQ4(4) MQ4(5) MQ4(6) MQ4(7) MQ4(8) MQ4(9)
    #undef MQ4
  }
  return s;
}

__global__ __launch_bounds__(NTB)
__attribute__((amdgpu_waves_per_eu(4)))
void state_kernel(const float* __restrict__ wd, const float* __restrict__ bd,
                  const float* __restrict__ wsf, float* __restrict__ out){
  extern __shared__ __align__(16) char smem[];
  v4f* S    = (v4f*)smem;                  // 10099 v4f (161584 B)
  cxf* uv   = (cxf*)(smem + 161584);       // 2 states * 4*10 encoding vectors
  v2f* red  = (v2f*)(smem + 162224);       // 16 waves

  const float* __restrict__ V   = wsf;            // for V^T gate
  const float* __restrict__ VT  = wsf + 100;      // for V gate
  const float* __restrict__ W   = wsf + 200;
  const cxf*   __restrict__ BSm = (const cxf*)(wsf + 1200);
  const cxf*   __restrict__ UL  = (const cxf*)(wsf + 5000);
  const cxf*   __restrict__ WU  = (const cxf*)(wsf + 9800);
  const cxf*   __restrict__ uw  = (const cxf*)(wsf + U_OFF);

  const int tid = threadIdx.x, wv = tid>>6, lane = tid&63;
  const int wid = __builtin_amdgcn_readfirstlane(tid) >> 6;  // scalar wave id
  const int b = blockIdx.x;                // batch items 2b, 2b+1

  if (tid < 80) uv[tid] = uw[b*80 + tid];
  __syncthreads();

  // Init: both product states, interleaved {re0,im0,re1,im1}.
  for (int e=tid; e<10000; e+=NTB){
    int c0=e/1000, r_=e-1000*c0, c1=r_/100, r2_=r_-100*c1, c2=r2_/10, c3=r2_-10*c2;
    cxf A0 = uv[c0],    B0 = uv[10+c1], C0 = uv[20+c2], D0 = uv[30+c3];
    cxf A1 = uv[40+c0], B1 = uv[50+c1], C1 = uv[60+c2], D1 = uv[70+c3];
    float pr = A0.x*B0.x - A0.y*B0.y, pi = A0.x*B0.y + A0.y*B0.x;
    float qr = pr*C0.x - pi*C0.y,  qi = pr*C0.y + pi*C0.x;
    float e0r = qr*D0.x - qi*D0.y, e0i = qr*D0.y + qi*D0.x;
    pr = A1.x*B1.x - A1.y*B1.y; pi = A1.x*B1.y + A1.y*B1.x;
    qr = pr*C1.x - pi*C1.y;  qi = pr*C1.y + pi*C1.x;
    float e1r = qr*D1.x - qi*D1.y, e1i = qr*D1.y + qi*D1.x;
    S[c0*1010 + c1*101 + c2*10 + c3] = (v4f){e0r, e0i, e1r, e1i};
  }
  __syncthreads();

  // ---------------- Layer 0 (commute-merged rounds) ----------------
  groupW0(S, W, wid, lane); __syncthreads();       // W(0,1)·W(0,2)·W(0,3)
  apply1_r4(S, VT, 0, tid); __syncthreads();      // V0
  apply1_r4(S, V, 1, tid);  __syncthreads();      // V1^T
  groupW1(S, W, wid, lane); __syncthreads();       // W(1,2)·W(1,3)
  apply1_r4(S, VT, 1, tid); __syncthreads();      // V1
  apply1_r4(S, V, 2, tid);  __syncthreads();      // V2^T
  applyW23(S, W, wid, lane); __syncthreads();      // W(2,3)
  apply1_r4(S, VT, 2, tid); __syncthreads();      // V2
  applyBS_u(S, BSm, 10, 1, 1010, 101, wid, lane); __syncthreads(); // BS(0,1)
  applyBS_u(S, BSm, 1010, 1, 101, 10, wid, lane); __syncthreads(); // BS(1,2)
  applyBS_u(S, BSm, 1010, 101, 10, 1, wid, lane); __syncthreads(); // BS(2,3)
  applyBS_u(S, BSm, 10, 101, 1, 1010, wid, lane); __syncthreads(); // BS(3,0)
  apply1_c4(S, UL, 0, tid); __syncthreads();      // UL0_L0 (carries L1's V0^T)

  // ---------------- Layer 1 ----------------
  groupWU0(S, WU, wid, lane); __syncthreads();     // WU(1)·WU(2)·WU(3)
  apply1_r4(S, VT, 0, tid); __syncthreads();      // V0
  apply1_r4(S, V, 1, tid);  __syncthreads();      // V1^T
  groupW1(S, W, wid, lane); __syncthreads();       // W(1,2)·W(1,3)
  apply1_r4(S, VT, 1, tid); __syncthreads();      // V1
  apply1_r4(S, V, 2, tid);  __syncthreads();      // V2^T
  applyW23(S, W, wid, lane); __syncthreads();      // W(2,3)
  apply1_r4(S, VT, 2, tid); __syncthreads();      // V2
  applyBS_u(S, BSm, 10, 1, 1010, 101, wid, lane); __syncthreads(); // BS(0,1)
  applyBS_u(S, BSm, 1010, 1, 101, 10, wid, lane); __syncthreads(); // BS(1,2)
  applyBS_u(S, BSm, 1010, 101, 10, 1, wid, lane); __syncthreads(); // BS(2,3)
  applyBS_u(S, BSm, 10, 101, 1, 1010, wid, lane); __syncthreads(); // BS(3,0)

  // Fused measurement: UL[L1,m] applied read-only; UL[L1,3] dropped.
  float w0 = wd[0], w1 = wd[1], w2 = wd[2];
  v2f m0 = measure14(S, UL + 400, 0, tid);
  v2f m1 = measure14(S, UL + 500, 1, tid);
  v2f m2 = measure14(S, UL + 600, 2, tid);
  v2f acc;
  acc.x = w0*m0.x + w1*m1.x + w2*m2.x;
  acc.y = w0*m0.y + w1*m1.y + w2*m2.y;

  for (int off=32; off; off>>=1){
    acc.x += __shfl_down(acc.x, off, 64);
    acc.y += __shfl_down(acc.y, off, 64);
  }
  if (lane == 0) red[wv] = acc;
  __syncthreads();
  if (tid == 0){
    float sx = 0.f, sy = 0.f;
    for (int i=0;i<16;i++){ sx += red[i].x; sy += red[i].y; }
    out[2*b+0] = sx + bd[0];
    out[2*b+1] = sy + bd[0];
  }
}

} // anonymous namespace

extern "C" void kernel_launch(void* const* d_in, const int* in_sizes, int n_in,
                              void* d_out, int out_size, void* d_ws, size_t ws_size,
                              hipStream_t stream){
  const float* jets   = (const float*)d_in[0];
  const float* sscale = (const float*)d_in[1];
  const float* dmag   = (const float*)d_in[2];
  const float* dphase = (const float*)d_in[3];
  const float* smag   = (const float*)d_in[4];
  const float* sphase = (const float*)d_in[5];
  const float* wd     = (const float*)d_in[6];
  const float* bd     = (const float*)d_in[7];
  float* out = (float*)d_out;
  float* wsf = (float*)d_ws;
  int B = in_sizes[0] / 12;

  (void)hipFuncSetAttribute(reinterpret_cast<const void*>(&state_kernel),
                            hipFuncAttributeMaxDynamicSharedMemorySize, SMEM_STATE);

  gates_kernel<<<12, 256, 0, stream>>>(dmag, dphase, smag, sphase, wsf);
  fuse_kernel<<<1, 512, 0, stream>>>(wsf);
  enc_kernel<<<B*4, 128, 0, stream>>>(jets, sscale, wsf);
  state_kernel<<<B/2, NTB, SMEM_STATE, stream>>>(wd, bd, wsf, out);
}

// Round 13
// 765.389 us; speedup vs baseline: 1.0168x; 1.0168x over previous
//
#include <hip/hip_runtime.h>
#include <math.h>

// CV-photonic circuit: WIRES=4, LAYERS=2, CUTOFF=10, BATCH=2048.
// R26 = R24 state_kernel (best measured: 598us) + barrier-free expm_f32
// (wave-private scr buffers need no block barriers) in gates/enc kernels.
// R25 round-packing reverted (neutral). See analysis above.

namespace {

constexpr int NTB = 1024;                 // threads per state block (16 waves)
constexpr int SMEM_STATE = 162352;        // 161584 state + 640 uv + 128 red
constexpr double THETA = 0.7853981633974483096; // pi/4

struct cxf { float x, y; };
typedef float v2f __attribute__((ext_vector_type(2)));
typedef float v4f __attribute__((ext_vector_type(4)));

// ws float layout: (unchanged, see prior rounds)
constexpr int U_OFF = 15872;

__device__ __forceinline__ cxf gen_squeeze_f(int i, int j, float zr, float zi){
  if (j == i+2){ float g = 0.5f*sqrtf((float)((i+1)*(i+2))); return {zr*g, -zi*g}; }
  if (i == j+2){ float g = 0.5f*sqrtf((float)((j+1)*(j+2))); return {-zr*g, -zi*g}; }
  return {0.f, 0.f};
}
__device__ __forceinline__ cxf gen_disp_f(int i, int j, float ar, float ai){
  if (i == j+1){ float g = sqrtf((float)i); return {ar*g, ai*g}; }
  if (j == i+1){ float g = sqrtf((float)j); return {-ar*g, ai*g}; }
  return {0.f, 0.f};
}

// Wave-cooperative fixed-schedule fp32 expm: result = exp(M), n x n (n<=10).
// BARRIER-FREE: buffers are wave-private (DS ops of a wave are in-order).
__device__ void expm_f32(bool act, int n, cxf* M, cxf* P, cxf* T, cxf* R, int lane){
  const int n2 = n*n;
  if (act){
    for (int e=lane; e<n2; e+=64){ M[e].x *= 0x1p-10f; M[e].y *= 0x1p-10f; }
    for (int e=lane; e<n2; e+=64){
      P[e] = M[e];
      cxf r = M[e];
      if (e % (n+1) == 0) r.x += 1.f;
      R[e] = r;
    }
    for (int t=2; t<=12; ++t){
      float inv = 1.f/(float)t;
      for (int e=lane; e<n2; e+=64){
        int i = e/n, j = e - i*n;
        float ax=0.f, ay=0.f;
        for (int k=0;k<n;k++){
          cxf p = P[i*n+k], m = M[k*n+j];
          ax += p.x*m.x - p.y*m.y;
          ay += p.x*m.y + p.y*m.x;
        }
        T[e] = {ax*inv, ay*inv};
      }
      { cxf* tmp = P; P = T; T = tmp; }
      for (int e=lane; e<n2; e+=64){ R[e].x += P[e].x; R[e].y += P[e].y; }
    }
    for (int s=0; s<10; ++s){
      for (int e=lane; e<n2; e+=64){
        int i = e/n, j = e - i*n;
        float ax=0.f, ay=0.f;
        for (int k=0;k<n;k++){
          cxf p = R[i*n+k], q = R[k*n+j];
          ax += p.x*q.x - p.y*q.y;
          ay += p.x*q.y + p.y*q.x;
        }
        T[e] = {ax, ay};
      }
      { cxf* tmp = R; R = T; T = tmp; }
    }
  }
}

// ------------- Kernel A: 45 expm tasks fully parallel over 12 blocks -------
__global__ __launch_bounds__(256)
void gates_kernel(const float* __restrict__ dmag, const float* __restrict__ dphase,
                  const float* __restrict__ smag, const float* __restrict__ sphase,
                  float* __restrict__ wsf){
  __shared__ double lam[10];
  __shared__ float scr[4][4][200];      // [wave][buf] cxf[100]
  const int tid = threadIdx.x;
  const int wv = tid >> 6, lane = tid & 63, g = blockIdx.x;
  float* ws_V  = wsf;
  float* ws_VT = wsf + 100;
  float* ws_W  = wsf + 200;
  cxf* ws_BS   = (cxf*)(wsf + 1200);
  cxf* ws_stage= (cxf*)(wsf + 6600);

  if (tid < 10){
    double lo = -6.0, hi = 6.0;
    for (int it=0; it<52; ++it){
      double mid = 0.5*(lo+hi);
      int cnt = 0;
      double pm1 = 1.0;
      double p = -mid;
      if (p == 0.0){ p = -1e-300; }
      if (p < 0.0) cnt++;
      for (int k=2; k<=10; ++k){
        double pn = -mid*p - (double)(k-1)*pm1;
        bool chg = (pn < 0.0) != (p < 0.0);
        if (pn == 0.0){ pn = (p < 0.0) ? 1e-300 : -1e-300; chg = true; }
        if (chg) cnt++;
        pm1 = p; p = pn;
      }
      if (cnt > tid) hi = mid; else lo = mid;
    }
    double x = 0.5*(lo+hi);
    double p[10];
    p[0] = 1.0; p[1] = x;
    for (int k=1;k<9;k++) p[k+1] = (x*p[k] - sqrt((double)k)*p[k-1]) * (1.0/sqrt((double)(k+1)));
    double nn=0.0; for (int k=0;k<10;k++) nn += p[k]*p[k];
    double inv = 1.0/sqrt(nn);
    lam[tid] = x;
    if (g == 0){
      for (int k=0;k<10;k++){
        float v = (float)(p[k]*inv);
        ws_V[k*10+tid]  = v;
        ws_VT[tid*10+k] = v;
      }
    }
  }
  __syncthreads();

  int t = g*4 + wv;
  bool act = (t < 45);
  int n = 10, bn = 0, ilo = 0;
  if (act && t >= 10 && t < 29){
    bn = t - 10; ilo = bn < 10 ? 0 : bn - 9;
    int ihi = bn < 10 ? bn : 9;
    n = ihi - ilo + 1;
  }
  cxf* M = (cxf*)scr[wv][0];
  cxf* P = (cxf*)scr[wv][1];
  cxf* T = (cxf*)scr[wv][2];
  cxf* R = (cxf*)scr[wv][3];
  if (act){
    if (t < 10){
      float l = (float)lam[t];
      for (int e=lane; e<100; e+=64){
        int i=e/10, j=e-10*i;
        float v = 0.f;
        if (j == i+1) v = -0.5f*l*sqrtf((float)(i+1));
        else if (i == j+1) v = 0.5f*l*sqrtf((float)i);
        M[e] = {v, 0.f};
      }
    } else if (t < 29){
      for (int e=lane; e<n*n; e+=64){
        int rr=e/n, c=e-n*rr;
        float v = 0.f;
        if (c == rr+1) v = (float)THETA*sqrtf((float)((ilo+rr+1)*(bn-ilo-rr)));
        else if (rr == c+1) v = (float)THETA*sqrtf((float)((ilo+c+1)*(bn-ilo-c)));
        M[e] = {0.f, v};
      }
    } else {
      int idx = t-29, kind = idx>>3, L=(idx>>2)&1, w=idx&3;
      float r_ = kind ? dmag[L*4+w]   : smag[L*4+w];
      float ph = kind ? dphase[L*4+w] : sphase[L*4+w];
      float zr = r_*cosf(ph), zi = r_*sinf(ph);
      for (int e=lane; e<100; e+=64){
        int i=e/10, j=e-10*i;
        M[e] = kind ? gen_disp_f(i,j,zr,zi) : gen_squeeze_f(i,j,zr,zi);
      }
    }
  }
  expm_f32(act, n, M, P, T, R, lane);
  if (act){
    if (t < 10){
      for (int e=lane;e<100;e+=64){
        int i=e/10, j=e-10*i;
        ws_W[t*100 + j*10 + i] = R[e].x;
      }
    } else if (t < 29){
      for (int e=lane;e<100;e+=64){
        int rr=e/10, c=e-10*rr;
        cxf o; o.x=0.f; o.y=0.f;
        if (rr < n && c < n) o = R[rr*n+c];
        ws_BS[bn*100 + c*10 + rr] = o;
      }
    } else {
      int idx = t-29;
      for (int e=lane;e<100;e+=64) ws_stage[idx*100 + e] = R[e];
    }
  }
}

// ---- Kernel A2: UL products, VT fold, and WU_b[n] = W_n * UL_b fusion -----
__global__ __launch_bounds__(512)
void fuse_kernel(float* __restrict__ wsf){
  __shared__ cxf ulraw[8][100];
  const int tid = threadIdx.x, wv = tid>>6, lane = tid&63;
  const cxf* stage = (const cxf*)(wsf + 6600);
  cxf* ws_UL = (cxf*)(wsf + 5000);
  cxf* ws_WU = (cxf*)(wsf + 9800);
  const float* V  = wsf;
  const float* Wt = wsf + 200;
  const cxf* Sm = stage + wv*100;
  const cxf* Dm = stage + (8+wv)*100;
  for (int e=lane; e<100; e+=64){
    int i=e/10, j=e-10*i;
    float ax=0.f, ay=0.f;
    for (int k=0;k<10;k++){
      cxf d=Dm[i*10+k], s=Sm[k*10+j];
      ax += d.x*s.x - d.y*s.y;
      ay += d.x*s.y + d.y*s.x;
    }
    ulraw[wv][e] = {ax, ay};
  }
  __syncthreads();
  cxf t0={0.f,0.f}, t1={0.f,0.f};
  if (wv == 0){
    {
      int e=lane, i=e/10, j=e-10*i;
      float ox=0.f, oy=0.f;
      for (int k=0;k<10;k++){ float v=V[k*10+i]; ox+=v*ulraw[0][k*10+j].x; oy+=v*ulraw[0][k*10+j].y; }
      t0 = {ox, oy};
    }
    if (lane+64 < 100){
      int e=lane+64, i=e/10, j=e-10*i;
      float ox=0.f, oy=0.f;
      for (int k=0;k<10;k++){ float v=V[k*10+i]; ox+=v*ulraw[0][k*10+j].x; oy+=v*ulraw[0][k*10+j].y; }
      t1 = {ox, oy};
    }
  }
  __syncthreads();
  if (wv == 0){
    ulraw[0][lane] = t0;
    if (lane+64 < 100) ulraw[0][lane+64] = t1;
  }
  __syncthreads();
  for (int e=tid; e<400; e+=512){
    int fi = e/100, r = e-100*fi;
    int f = (fi==0) ? 0 : (3+fi);
    int i=r/10, j=r-10*i;
    ws_UL[f*100 + j*10 + i] = ulraw[f][i*10+j];
  }
  for (int round=0; round<4; ++round){
    int id = round*8 + wv;
    if (id < 30){
      int b = 1 + id/10, n = id - (id/10)*10;
      const cxf* Ub = ulraw[b];
      for (int e=lane; e<100; e+=64){
        int i=e/10, j=e-10*i;
        float ax=0.f, ay=0.f;
        for (int k=0;k<10;k++){
          float w = Wt[n*100 + k*10 + i];
          ax += w*Ub[k*10+j].x;
          ay += w*Ub[k*10+j].y;
        }
        cxf o; o.x=ax; o.y=ay;
        ws_WU[id*100 + j*10 + i] = o;
      }
    }
  }
}

// ------------- Kernel B: per-(b,w) encoding vector u = D*(S*e0), fp32 ------
__global__ __launch_bounds__(128)
void enc_kernel(const float* __restrict__ jets, const float* __restrict__ sscale,
                float* __restrict__ wsf){
  __shared__ float scr[2][4][200];
  __shared__ cxf col[10];
  __shared__ cxf uacc[10];
  const int tid = threadIdx.x, wv = tid>>6, lane = tid&63;
  const int blk = blockIdx.x, b = blk>>2, w = blk&3;

  float eta = jets[b*12 + w*3 + 0];
  float jph = jets[b*12 + w*3 + 1];
  float pt  = jets[b*12 + w*3 + 2];

  cxf* M = (cxf*)scr[wv][0];
  cxf* P = (cxf*)scr[wv][1];
  cxf* T = (cxf*)scr[wv][2];
  cxf* R = (cxf*)scr[wv][3];
  {
    float zr, zi;
    if (wv == 0){ float phs = pt*jph*0.5f; zr = eta*cosf(phs); zi = eta*sinf(phs); }
    else {
      double sc = 10.0/(1.0 + exp(-(double)sscale[0])) + 0.01;
      float mag = (float)sc*pt; zr = mag*cosf(eta); zi = mag*sinf(eta);
    }
    for (int e=lane; e<100; e+=64){
      int i=e/10, j=e-10*i;
      M[e] = wv ? gen_disp_f(i,j,zr,zi) : gen_squeeze_f(i,j,zr,zi);
    }
  }
  expm_f32(true, 10, M, P, T, R, lane);
  cxf* Rs = (cxf*)scr[0][3];
  cxf* Rd = (cxf*)scr[1][3];
  if (tid < 10) col[tid] = Rs[tid*10];           // own-wave read
  __syncthreads();                               // wave 1 expm done; col visible
  if (tid < 10){
    float ax=0.f, ay=0.f;
    for (int k=0;k<10;k++){
      cxf d = Rd[tid*10+k], c = col[k];
      ax += d.x*c.x - d.y*c.y;
      ay += d.x*c.y + d.y*c.x;
    }
    uacc[tid] = {ax, ay};
  }
  __syncthreads();
  if (tid < 10){
    float rx, ry;
    if (w == 0){
      rx = 0.f; ry = 0.f;
      for (int k=0;k<10;k++){
        float v = wsf[k*10 + tid];
        rx += v*uacc[k].x;
        ry += v*uacc[k].y;
      }
    } else { rx = uacc[tid].x; ry = uacc[tid].y; }
    float* u_out = wsf + U_OFF + (b*40 + w*10 + tid)*2;
    u_out[0] = rx;
    u_out[1] = ry;
  }
}

// ---------------- Kernel C: the circuit (R24, unchanged) -------------------
__device__ __forceinline__ constexpr int WS(int w){
  return w==0 ? 1010 : (w==1 ? 101 : (w==2 ? 10 : 1));
}

#define DECLP(P) v4f P##0={0.f,0.f,0.f,0.f}, P##1=P##0, P##2=P##0, P##3=P##0, \
  P##4=P##0, P##5=P##0, P##6=P##0, P##7=P##0, P##8=P##0, P##9=P##0;

#define REX(O,i,u) O##i = __builtin_elementwise_fma((v4f){(u),(u),(u),(u)}, vv, O##i);

#define RPAIRX(O, va, vb, Mp_) { \
  const v4f* Mp = (Mp_); \
  v4f q0=Mp[0],q1=Mp[1],q2=Mp[2],q3=Mp[3],q4=Mp[4]; \
  { v4f vv=va; REX(O,0,q0.x) REX(O,1,q0.y) REX(O,2,q0.z) REX(O,3,q0.w) REX(O,4,q1.x) \
               REX(O,5,q1.y) REX(O,6,q1.z) REX(O,7,q1.w) REX(O,8,q2.x) REX(O,9,q2.y) } \
  { v4f vv=vb; REX(O,0,q2.z) REX(O,1,q2.w) REX(O,2,q3.x) REX(O,3,q3.y) REX(O,4,q3.z) \
               REX(O,5,q3.w) REX(O,6,q4.x) REX(O,7,q4.y) REX(O,8,q4.z) REX(O,9,q4.w) } }

#define RSTAGE(Mt, I, O) \
  RPAIRX(O, I##0, I##1, (const v4f*)((Mt)+0))  \
  RPAIRX(O, I##2, I##3, (const v4f*)((Mt)+20)) \
  RPAIRX(O, I##4, I##5, (const v4f*)((Mt)+40)) \
  RPAIRX(O, I##6, I##7, (const v4f*)((Mt)+60)) \
  RPAIRX(O, I##8, I##9, (const v4f*)((Mt)+80))

#define CEX(O,i,ur,ui) \
  O##i = __builtin_elementwise_fma((v4f){(ur),(ur),(ur),(ur)}, vv, O##i); \
  O##i = __builtin_elementwise_fma((v4f){-(ui),(ui),-(ui),(ui)}, vs, O##i);

#define CROWX(O, vk, Up_) { \
  const v4f* Up = (Up_); \
  v4f q0=Up[0],q1=Up[1],q2=Up[2],q3=Up[3],q4=Up[4]; \
  v4f vv=vk, vs=__builtin_shufflevector(vk,vk,1,0,3,2); \
  CEX(O,0,q0.x,q0.y) CEX(O,1,q0.z,q0.w) CEX(O,2,q1.x,q1.y) CEX(O,3,q1.z,q1.w) \
  CEX(O,4,q2.x,q2.y) CEX(O,5,q2.z,q2.w) CEX(O,6,q3.x,q3.y) CEX(O,7,q3.z,q3.w) \
  CEX(O,8,q4.x,q4.y) CEX(O,9,q4.z,q4.w) }

#define CROWX9(O, vk, Up_) { \
  const v4f* Up = (Up_); \
  v4f q0=Up[0],q1=Up[1],q2=Up[2],q3=Up[3],q4=Up[4]; \
  v4f vv=vk, vs=__builtin_shufflevector(vk,vk,1,0,3,2); \
  CEX(O,1,q0.z,q0.w) CEX(O,2,q1.x,q1.y) CEX(O,3,q1.z,q1.w) \
  CEX(O,4,q2.x,q2.y) CEX(O,5,q2.z,q2.w) CEX(O,6,q3.x,q3.y) CEX(O,7,q3.z,q3.w) \
  CEX(O,8,q4.x,q4.y) CEX(O,9,q4.z,q4.w) }

#define CSTAGE(U, I, O) \
  CROWX(O, I##0, (const v4f*)((U)+0))  CROWX(O, I##1, (const v4f*)((U)+10)) \
  CROWX(O, I##2, (const v4f*)((U)+20)) CROWX(O, I##3, (const v4f*)((U)+30)) \
  CROWX(O, I##4, (const v4f*)((U)+40)) CROWX(O, I##5, (const v4f*)((U)+50)) \
  CROWX(O, I##6, (const v4f*)((U)+60)) CROWX(O, I##7, (const v4f*)((U)+70)) \
  CROWX(O, I##8, (const v4f*)((U)+80)) CROWX(O, I##9, (const v4f*)((U)+90))

#define CSTAGE9(U, I, O) \
  CROWX9(O, I##0, (const v4f*)((U)+0))  CROWX9(O, I##1, (const v4f*)((U)+10)) \
  CROWX9(O, I##2, (const v4f*)((U)+20)) CROWX9(O, I##3, (const v4f*)((U)+30)) \
  CROWX9(O, I##4, (const v4f*)((U)+40)) CROWX9(O, I##5, (const v4f*)((U)+50)) \
  CROWX9(O, I##6, (const v4f*)((U)+60)) CROWX9(O, I##7, (const v4f*)((U)+70)) \
  CROWX9(O, I##8, (const v4f*)((U)+80)) CROWX9(O, I##9, (const v4f*)((U)+90))

#define LDS_RD10 \
  v4f r0=S[base], r1=S[base+sm], r2=S[base+2*sm], r3=S[base+3*sm], r4=S[base+4*sm], \
      r5=S[base+5*sm], r6=S[base+6*sm], r7=S[base+7*sm], r8=S[base+8*sm], r9=S[base+9*sm];

#define PSTORE10(P) { S[base]=P##0; S[base+sm]=P##1; S[base+2*sm]=P##2; S[base+3*sm]=P##3; \
  S[base+4*sm]=P##4; S[base+5*sm]=P##5; S[base+6*sm]=P##6; S[base+7*sm]=P##7; \
  S[base+8*sm]=P##8; S[base+9*sm]=P##9; }

__device__ __forceinline__ void do_Wtask(v4f* S, const float* __restrict__ Wall,
                                         int sc, int sm, int sa, int sb,
                                         int t, int lane){
  int n = t>>1, half = t&1;
  if (lane < 50){
    int f = half*50 + lane;
    int qa = f/10, qb = f - 10*qa;
    int base = n*sc + qa*sa + qb*sb;
    const float* __restrict__ Mt = Wall + n*100;
    LDS_RD10
    DECLP(a) RSTAGE(Mt, r, a)
    PSTORE10(a)
  }
}
__device__ __forceinline__ void applyW_u(v4f* S, const float* __restrict__ Wall,
                                         int sc, int sm, int sa, int sb,
                                         int wid, int lane){
  do_Wtask(S, Wall, sc, sm, sa, sb, wid, lane);
  if (wid < 4) do_Wtask(S, Wall, sc, sm, sa, sb, 16+wid, lane);
}

__device__ __forceinline__ void do_WUtask(v4f* S, const cxf* __restrict__ WUb,
                                          int sc, int sm, int sa, int sb,
                                          int t, int lane){
  int n = t>>1, half = t&1;
  if (lane < 50){
    int f = half*50 + lane;
    int qa = f/10, qb = f - 10*qa;
    int base = n*sc + qa*sa + qb*sb;
    const cxf* __restrict__ U = WUb + n*100;
    LDS_RD10
    DECLP(a) CSTAGE(U, r, a)
    PSTORE10(a)
  }
}
__device__ __forceinline__ void applyWU_u(v4f* S, const cxf* __restrict__ WUb,
                                          int sc, int sm, int sa, int sb,
                                          int wid, int lane){
  do_WUtask(S, WUb, sc, sm, sa, sb, wid, lane);
  if (wid < 4) do_WUtask(S, WUb, sc, sm, sa, sb, 16+wid, lane);
}

__device__ __forceinline__ void do_BStask(v4f* S, const cxf* __restrict__ BSp,
                                          int sa, int sb, int s1, int s2, int ds,
                                          int t, int lane){
  int bn = t>>1, half = t&1;
  int ilo = bn<10?0:bn-9, ihi = bn<10?bn:9, sz = ihi-ilo+1;
  if (lane < 50){
    int f = half*50 + lane;
    int ca = f/10, cb = f - 10*ca;
    int base = ca*sa + cb*sb;
    const cxf* __restrict__ Bt = BSp + bn*100;
    DECLP(a)
    int radr = base + ilo*s1 + (bn-ilo)*s2;
    int kk = 0;
    #pragma unroll 1
    for (int c=0;c<sz;c++){
      v4f rk = S[radr];
      CROWX(a, rk, (const v4f*)(Bt + kk))
      radr += ds; kk += 10;
    }
    int wadr = base + ilo*s1 + (bn-ilo)*s2;
    #define BSTQ(r) if ((r) < sz){ S[wadr] = a##r; wadr += ds; }
    BSTQ(0) BSTQ(1) BSTQ(2) BSTQ(3) BSTQ(4) BSTQ(5) BSTQ(6) BSTQ(7) BSTQ(8) BSTQ(9)
    #undef BSTQ
  }
}
__device__ __forceinline__ void applyBS_u(v4f* S, const cxf* __restrict__ BSp,
                                          int sa, int sb, int s1, int s2,
                                          int wid, int lane){
  const int ds = s1 - s2;
  do_BStask(S, BSp, sa, sb, s1, s2, ds, wid, lane);
  do_BStask(S, BSp, sa, sb, s1, s2, ds, wid+16, lane);
  if (wid < 6) do_BStask(S, BSp, sa, sb, s1, s2, ds, wid+32, lane);
}

__device__ __forceinline__ void apply1_r4(v4f* S, const float* __restrict__ Mt, int m, int tid){
  const int sm = WS(m);
  const int x0 = (m==0)?1:0, x1=(m<=1)?2:1, x2=(m<=2)?3:2;
  const int s0 = WS(x0), s1 = WS(x1), s2 = WS(x2);
  if (tid < 1000){
    int d0=tid/100, rem=tid-100*d0, d1=rem/10, d2=rem-10*d1;
    int base = d0*s0 + d1*s1 + d2*s2;
    LDS_RD10
    DECLP(a) RSTAGE(Mt, r, a)
    PSTORE10(a)
  }
}

__device__ __forceinline__ void apply1_c4(v4f* S, const cxf* __restrict__ U, int m, int tid){
  const int sm = WS(m);
  const int x0 = (m==0)?1:0, x1=(m<=1)?2:1, x2=(m<=2)?3:2;
  const int s0 = WS(x0), s1 = WS(x1), s2 = WS(x2);
  if (tid < 1000){
    int d0=tid/100, rem=tid-100*d0, d1=rem/10, d2=rem-10*d1;
    int base = d0*s0 + d1*s1 + d2*s2;
    LDS_RD10
    DECLP(a) CSTAGE(U, r, a)
    PSTORE10(a)
  }
}

__device__ __forceinline__ v2f measure14(const v4f* S, const cxf* __restrict__ U, int m, int tid){
  const int sm = WS(m);
  const int x0 = (m==0)?1:0, x1=(m<=1)?2:1, x2=3;
  const int s0 = WS(x0), s1 = WS(x1), s2 = WS(x2);
  v2f s = {0.f, 0.f};
  if (tid < 1000){
    int d0=tid/100, rem=tid-100*d0, d1=rem/10, d2=rem-10*d1;
    int base = d0*s0 + d1*s1 + d2*s2;
    LDS_RD10
    DECLP(a) CSTAGE9(U, r, a)
    #define MQ4(i) { s.x += (float)(i)*(a##i.x*a##i.x + a##i.y*a##i.y); \
                     s.y += (float)(i)*(a##i.z*a##i.z + a##i.w*a##i.w); }
    MQ4(1) MQ4(2) MQ4(3) MQ4(4) MQ4(5) MQ4(6) MQ4(7) MQ4(8) MQ4(9)
    #undef MQ4
  }
  return s;
}

__global__ __launch_bounds__(NTB)
__attribute__((amdgpu_waves_per_eu(4)))
void state_kernel(const float* __restrict__ wd, const float* __restrict__ bd,
                  const float* __restrict__ wsf, float* __restrict__ out){
  extern __shared__ __align__(16) char smem[];
  v4f* S    = (v4f*)smem;
  cxf* uv   = (cxf*)(smem + 161584);
  v2f* red  = (v2f*)(smem + 162224);

  const float* __restrict__ V   = wsf;
  const float* __restrict__ VT  = wsf + 100;
  const float* __restrict__ W   = wsf + 200;
  const cxf*   __restrict__ BSm = (const cxf*)(wsf + 1200);
  const cxf*   __restrict__ UL  = (const cxf*)(wsf + 5000);
  const cxf*   __restrict__ WU  = (const cxf*)(wsf + 9800);
  const cxf*   __restrict__ uw  = (const cxf*)(wsf + U_OFF);

  const int tid = threadIdx.x, wv = tid>>6, lane = tid&63;
  const int wid = __builtin_amdgcn_readfirstlane(tid) >> 6;
  const int b = blockIdx.x;

  if (tid < 80) uv[tid] = uw[b*80 + tid];
  __syncthreads();

  for (int e=tid; e<10000; e+=NTB){
    int c0=e/1000, r_=e-1000*c0, c1=r_/100, r2_=r_-100*c1, c2=r2_/10, c3=r2_-10*c2;
    cxf A0 = uv[c0],    B0 = uv[10+c1], C0 = uv[20+c2], D0 = uv[30+c3];
    cxf A1 = uv[40+c0], B1 = uv[50+c1], C1 = uv[60+c2], D1 = uv[70+c3];
    float pr = A0.x*B0.x - A0.y*B0.y, pi = A0.x*B0.y + A0.y*B0.x;
    float qr = pr*C0.x - pi*C0.y,  qi = pr*C0.y + pi*C0.x;
    float e0r = qr*D0.x - qi*D0.y, e0i = qr*D0.y + qi*D0.x;
    pr = A1.x*B1.x - A1.y*B1.y; pi = A1.x*B1.y + A1.y*B1.x;
    qr = pr*C1.x - pi*C1.y;  qi = pr*C1.y + pi*C1.x;
    float e1r = qr*D1.x - qi*D1.y, e1i = qr*D1.y + qi*D1.x;
    S[c0*1010 + c1*101 + c2*10 + c3] = (v4f){e0r, e0i, e1r, e1i};
  }
  __syncthreads();

  applyW_u(S, W, 1010, 101, 10, 1, wid, lane); __syncthreads();
  applyW_u(S, W, 1010, 10, 101, 1, wid, lane); __syncthreads();
  applyW_u(S, W, 1010, 1, 10, 101, wid, lane); __syncthreads();
  apply1_r4(S, VT, 0, tid); __syncthreads();
  apply1_r4(S, V, 1, tid);  __syncthreads();
  applyW_u(S, W, 101, 10, 1010, 1, wid, lane); __syncthreads();
  applyW_u(S, W, 101, 1, 1010, 10, wid, lane); __syncthreads();
  apply1_r4(S, VT, 1, tid); __syncthreads();
  apply1_r4(S, V, 2, tid);  __syncthreads();
  applyW_u(S, W, 10, 1, 1010, 101, wid, lane); __syncthreads();
  apply1_r4(S, VT, 2, tid); __syncthreads();
  applyBS_u(S, BSm, 10, 1, 1010, 101, wid, lane); __syncthreads();
  applyBS_u(S, BSm, 1010, 1, 101, 10, wid, lane); __syncthreads();
  applyBS_u(S, BSm, 1010, 101, 10, 1, wid, lane); __syncthreads();
  applyBS_u(S, BSm, 10, 101, 1, 1010, wid, lane); __syncthreads();
  apply1_c4(S, UL, 0, tid); __syncthreads();

  applyWU_u(S, WU,        1010, 101, 10, 1, wid, lane); __syncthreads();
  applyWU_u(S, WU + 1000, 1010, 10, 101, 1, wid, lane); __syncthreads();
  applyWU_u(S, WU + 2000, 1010, 1, 10, 101, wid, lane); __syncthreads();
  apply1_r4(S, VT, 0, tid); __syncthreads();
  apply1_r4(S, V, 1, tid);  __syncthreads();
  applyW_u(S, W, 101, 10, 1010, 1, wid, lane); __syncthreads();
  applyW_u(S, W, 101, 1, 1010, 10, wid, lane); __syncthreads();
  apply1_r4(S, VT, 1, tid); __syncthreads();
  apply1_r4(S, V, 2, tid);  __syncthreads();
  applyW_u(S, W, 10, 1, 1010, 101, wid, lane); __syncthreads();
  apply1_r4(S, VT, 2, tid); __syncthreads();
  applyBS_u(S, BSm, 10, 1, 1010, 101, wid, lane); __syncthreads();
  applyBS_u(S, BSm, 1010, 1, 101, 10, wid, lane); __syncthreads();
  applyBS_u(S, BSm, 1010, 101, 10, 1, wid, lane); __syncthreads();
  applyBS_u(S, BSm, 10, 101, 1, 1010, wid, lane); __syncthreads();

  float w0 = wd[0], w1 = wd[1], w2 = wd[2];
  v2f m0 = measure14(S, UL + 400, 0, tid);
  v2f m1 = measure14(S, UL + 500, 1, tid);
  v2f m2 = measure14(S, UL + 600, 2, tid);
  v2f acc;
  acc.x = w0*m0.x + w1*m1.x + w2*m2.x;
  acc.y = w0*m0.y + w1*m1.y + w2*m2.y;

  for (int off=32; off; off>>=1){
    acc.x += __shfl_down(acc.x, off, 64);
    acc.y += __shfl_down(acc.y, off, 64);
  }
  if (lane == 0) red[wv] = acc;
  __syncthreads();
  if (tid == 0){
    float sx = 0.f, sy = 0.f;
    for (int i=0;i<16;i++){ sx += red[i].x; sy += red[i].y; }
    out[2*b+0] = sx + bd[0];
    out[2*b+1] = sy + bd[0];
  }
}

} // anonymous namespace

extern "C" void kernel_launch(void* const* d_in, const int* in_sizes, int n_in,
                              void* d_out, int out_size, void* d_ws, size_t ws_size,
                              hipStream_t stream){
  const float* jets   = (const float*)d_in[0];
  const float* sscale = (const float*)d_in[1];
  const float* dmag   = (const float*)d_in[2];
  const float* dphase = (const float*)d_in[3];
  const float* smag   = (const float*)d_in[4];
  const float* sphase = (const float*)d_in[5];
  const float* wd     = (const float*)d_in[6];
  const float* bd     = (const float*)d_in[7];
  float* out = (float*)d_out;
  float* wsf = (float*)d_ws;
  int B = in_sizes[0] / 12;

  (void)hipFuncSetAttribute(reinterpret_cast<const void*>(&state_kernel),
                            hipFuncAttributeMaxDynamicSharedMemorySize, SMEM_STATE);

  gates_kernel<<<12, 256, 0, stream>>>(dmag, dphase, smag, sphase, wsf);
  fuse_kernel<<<1, 512, 0, stream>>>(wsf);
  enc_kernel<<<B*4, 128, 0, stream>>>(jets, sscale, wsf);
  state_kernel<<<B/2, NTB, SMEM_STATE, stream>>>(wd, bd, wsf, out);
}